// Round 7
// baseline (540.846 us; speedup 1.0000x reference)
//
#include <hip/hip_runtime.h>
#include <hip/hip_fp16.h>

// Problem constants (fixed by the reference)
constexpr int NN    = 1024;  // tokens
constexpr int CZ    = 128;   // channels
constexpr int INDIM = 139;   // 4*32 + 2*2 + 7
// weight columns: [0,66) = pos, [66,132) = token, 132 = entity, [133,139) = chain

typedef float f4 __attribute__((ext_vector_type(4)));

// fp16 table layout (element indices, __half):
//   Ph[66][128] @ 0 | Th[66][128] @ 8448 | Ch[6][128] @ 16896
// Values are exactly the fp16-quantized weights, so storing the half BITS is
// exact. Entity column stays fp32 (chain+entity sum is not fp16-representable)
// and lives in registers (4 floats per lane).
constexpr int H_TOTAL  = 17664;               // halves = 35328 B
constexpr int H_BYTES  = H_TOTAL * 2;
constexpr int H_F4     = H_BYTES / 16;        // 2208 float4 chunks

// d_ws layout (bytes):
//   [0, 35328)        half tables
//   [35328, 35840)    entity fp32[128] (fp16 round-tripped values)
//   [35840, 39936)    packed attrs, one uint32 per token:
//                     asym[2:0] ent[4:3] sym[6:5] resi[16:7] tok[28:17]

struct __attribute__((aligned(8))) h4 { __half a, b, c, d; };

__device__ __forceinline__ f4 h4_to_f4(h4 h) {
    f4 r;
    r.x = __half2float(h.a); r.y = __half2float(h.b);
    r.z = __half2float(h.c); r.w = __half2float(h.d);
    return r;
}

// ---------------- kernel A: build fp16 tables + packed attrs ---------------
__global__ void build_tables(const int* __restrict__ asym, const int* __restrict__ resi,
                             const int* __restrict__ ent,  const int* __restrict__ tok,
                             const int* __restrict__ sym,  const float* __restrict__ w,
                             __half* __restrict__ htbl, float* __restrict__ entf,
                             unsigned* __restrict__ packed)
{
    const int gtid   = blockIdx.x * 256 + threadIdx.x;
    const int stride = gridDim.x * 256;

    for (int idx = gtid; idx < 8448; idx += stride) {
        const int d = idx >> 7, c = idx & 127;
        htbl[idx]        = __float2half(w[c * INDIM + d]);        // pos
        htbl[8448 + idx] = __float2half(w[c * INDIM + 66 + d]);   // token
    }
    for (int idx = gtid; idx < 768; idx += stride) {
        const int d = idx >> 7, c = idx & 127;
        htbl[16896 + idx] = __float2half(w[c * INDIM + 133 + d]); // chain
    }
    for (int c = gtid; c < CZ; c += stride)
        entf[c] = __half2float(__float2half(w[c * INDIM + 132])); // entity
    for (int j = gtid; j < NN; j += stride) {
        packed[j] = (unsigned)(asym[j] & 7)
                  | ((unsigned)(ent[j]  & 3)    << 3)
                  | ((unsigned)(sym[j]  & 3)    << 5)
                  | ((unsigned)(resi[j] & 1023) << 7)
                  | ((unsigned)(tok[j]  & 4095) << 17);
    }
}

// ---------------- kernel B: main streaming kernel --------------------------
// grid = 1024 blocks, 4 blocks/CU (39.4 KiB LDS), all co-resident.
// Block handles one i-row, all 1024 j. 4 waves/SIMD for latency hiding.
__global__ __launch_bounds__(256, 4) void relpos_main(
    const __half* __restrict__ htbl, const float* __restrict__ entf,
    const unsigned* __restrict__ packed, float* __restrict__ out)
{
    __shared__ __attribute__((aligned(16))) __half   hl[H_TOTAL];
    __shared__ __attribute__((aligned(16))) unsigned attrs[NN];

    const int tid = threadIdx.x;

    // coalesced contiguous table copy: 2208 float4 (8.6 per thread)
    {
        const f4* __restrict__ src = (const f4*)htbl;
        f4* __restrict__ dst = (f4*)hl;
        #pragma unroll
        for (int k = 0; k < 9; ++k) {
            const int idx = tid + 256 * k;
            if (idx < H_F4) dst[idx] = src[idx];
        }
    }
    #pragma unroll
    for (int k = 0; k < 4; ++k) attrs[tid + 256 * k] = packed[tid + 256 * k];

    const int g  = tid >> 5;          // pair-group 0..7 (8 j's per iteration)
    const int c4 = (tid & 31) << 2;   // channel base, float4 per lane
    const f4 ev = *(const f4*)&entf[c4];   // entity slice, register-resident

    __syncthreads();

    const int i = blockIdx.x;
    const unsigned pi = attrs[i];
    const int a0 = pi & 7, e0 = (pi >> 3) & 3, s0 = (pi >> 5) & 3;
    const int r0 = (pi >> 7) & 1023, t0 = (pi >> 17) & 4095;

    float* outp = out + ((size_t)i << 17) + (size_t)g * CZ + c4;

    #pragma unroll 4
    for (int jt = 0; jt < 128; ++jt) {
        const unsigned pj = attrs[jt * 8 + g];
        const int aj = pj & 7, ej = (pj >> 3) & 3, sj = (pj >> 5) & 3;
        const int rj = (pj >> 7) & 1023, tj = (pj >> 17) & 4095;

        const bool sc  = (a0 == aj);
        const bool sr  = (r0 == rj);
        const bool seb = (e0 == ej);

        int dres = min(max(r0 - rj + 32, 0), 64);
        if (!sc) dres = 65;
        int dtok = min(max(t0 - tj + 32, 0), 64);
        if (!(sc && sr)) dtok = 65;
        int dch = min(max(s0 - sj + 2, 0), 4);
        if (!seb) dch = 5;
        const float sef = seb ? 1.0f : 0.0f;

        const h4 ph = *(const h4*)&hl[dres * 128 + c4];
        const h4 th = *(const h4*)&hl[8448 + dtok * 128 + c4];
        const h4 ch = *(const h4*)&hl[16896 + dch * 128 + c4];

        f4 o = h4_to_f4(ph) + h4_to_f4(th);   // exact fp32 sums of fp16 values
        o = o + h4_to_f4(ch);
        o = o + sef * ev;                      // +entity iff same_ent (exact)

        *(f4*)outp = o;
        outp += 8 * CZ;   // advance 8 j-rows
    }
}

extern "C" void kernel_launch(void* const* d_in, const int* in_sizes, int n_in,
                              void* d_out, int out_size, void* d_ws, size_t ws_size,
                              hipStream_t stream) {
    const int*   asym   = (const int*)d_in[0];
    const int*   resi   = (const int*)d_in[1];
    const int*   ent    = (const int*)d_in[2];
    const int*   tok    = (const int*)d_in[3];
    const int*   sym    = (const int*)d_in[4];
    const float* weight = (const float*)d_in[5];
    float*       out    = (float*)d_out;

    __half*   htbl   = (__half*)d_ws;
    float*    entf   = (float*)((char*)d_ws + H_BYTES);
    unsigned* packed = (unsigned*)((char*)d_ws + H_BYTES + 512);

    build_tables<<<16, 256, 0, stream>>>(asym, resi, ent, tok, sym, weight,
                                         htbl, entf, packed);
    relpos_main<<<NN, 256, 0, stream>>>(htbl, entf, packed, out);
}